// Round 4
// baseline (337.808 us; speedup 1.0000x reference)
//
#include <hip/hip_runtime.h>
#include <hip/hip_bf16.h>

#define NNODE 50000
#define NEDGE 640000
#define NREL  3
#define HIDD  128
#define GNUM  512
#define K1    112   // layer-1 GEMM K (99 used + 13 zero pad)
#define K2    512   // layer-2 GEMM K (3*128 relations + 128 root)
#define NB    196   // scan blocks = ceil(NNODE/256)

typedef float  f32x4   __attribute__((ext_vector_type(4)));
typedef short  vshort8 __attribute__((ext_vector_type(8)));
typedef short  vshort4 __attribute__((ext_vector_type(4)));

// ---------------- builders ----------------
__global__ void build_tabs_kernel(const float* __restrict__ shape_w,
                                  const float* __restrict__ color_w,
                                  const float* __restrict__ W1,
                                  const float* __restrict__ root1,
                                  float* __restrict__ B1eff,
                                  float* __restrict__ rootTab) {
    int idx = blockIdx.x * blockDim.x + threadIdx.x;
    if (idx >= 4 * 33 * 128) return;
    int h  = idx & 127;
    int j  = (idx >> 7) % 33;
    int rr = idx / (33 * 128);
    const float* Wsrc = (rr < 3) ? (W1 + (size_t)rr * 129 * 128) : root1; // [129][128]
    float v = 0.f;
    if (j < 16) {
        for (int e = 0; e < 64; ++e) v += shape_w[j * 64 + e] * Wsrc[e * 128 + h];
    } else if (j < 32) {
        int c = j - 16;
        for (int e = 0; e < 64; ++e) v += color_w[c * 64 + e] * Wsrc[(64 + e) * 128 + h];
    } else {
        v = Wsrc[128 * 128 + h];
    }
    if (rr < 3) B1eff[(rr * 33 + j) * 128 + h] = v;
    else        rootTab[j * 128 + h] = v;
}

__device__ __forceinline__ void split_bf16(float f, short& hi, short& lo) {
    unsigned u  = __float_as_uint(f);
    unsigned uh = (u + 0x7FFFu + ((u >> 16) & 1u)) >> 16;
    hi = (short)uh;
    float fl = f - __uint_as_float(uh << 16);
    unsigned ul  = __float_as_uint(fl);
    unsigned ulh = (ul + 0x7FFFu + ((ul >> 16) & 1u)) >> 16;
    lo = (short)ulh;
}

__device__ __forceinline__ short bf16_rne(float f) {
    unsigned u = __float_as_uint(f);
    return (short)((u + 0x7FFFu + ((u >> 16) & 1u)) >> 16);
}

// B2 transposed + split: Bt[n][k], k<384 -> W2, else root2
__global__ void build_B2t_kernel(const float* __restrict__ W2,
                                 const float* __restrict__ root2,
                                 short* __restrict__ Bt_hi,
                                 short* __restrict__ Bt_lo) {
    int idx = blockIdx.x * blockDim.x + threadIdx.x; // 512*128
    if (idx >= K2 * 128) return;
    int k = idx >> 7, n = idx & 127;
    float v = (k < 384) ? W2[idx] : root2[idx - 384 * 128];
    short h, l;
    split_bf16(v, h, l);
    Bt_hi[(size_t)n * K2 + k] = h;
    Bt_lo[(size_t)n * K2 + k] = l;
}

// ---------------- edge counting (1 int atomic/edge) + node-feature pack ----------------
__global__ void count_nf_kernel(const int* __restrict__ ei, const int* __restrict__ et,
                                const int* __restrict__ shape_id, const int* __restrict__ color_id,
                                const float* __restrict__ pos,
                                int* __restrict__ cnt, int2* __restrict__ nf) {
    int e = blockIdx.x * blockDim.x + threadIdx.x;
    if (e < NNODE) nf[e] = make_int2(shape_id[e] | (color_id[e] << 8), __float_as_int(pos[e]));
    if (e >= NEDGE) return;
    int d = ei[NEDGE + e], r = et[e];
    atomicAdd(&cnt[d * 3 + r], 1);
}

// ---------------- prefix scan over per-node degree (3-phase) ----------------
__global__ void scan_partial_kernel(const int* __restrict__ cnt, int* __restrict__ partial) {
    __shared__ int sh[256];
    int t = threadIdx.x, i = blockIdx.x * 256 + t;
    int v = (i < NNODE) ? cnt[3 * i] + cnt[3 * i + 1] + cnt[3 * i + 2] : 0;
    sh[t] = v; __syncthreads();
    for (int o = 128; o > 0; o >>= 1) { if (t < o) sh[t] += sh[t + o]; __syncthreads(); }
    if (t == 0) partial[blockIdx.x] = sh[0];
}

__global__ void scan_mid_kernel(const int* __restrict__ partial, int* __restrict__ partial_pre,
                                int* __restrict__ offs) {
    __shared__ int sh[256];
    int t = threadIdx.x;
    int v = (t < NB) ? partial[t] : 0;
    sh[t] = v; __syncthreads();
    for (int o = 1; o < 256; o <<= 1) {
        int x = (t >= o) ? sh[t - o] : 0; __syncthreads();
        sh[t] += x; __syncthreads();
    }
    if (t < NB) partial_pre[t] = sh[t] - v;
    if (t == 0) offs[NNODE] = NEDGE;
}

__global__ void scan_final_kernel(const int* __restrict__ cnt, const int* __restrict__ partial_pre,
                                  int* __restrict__ offs, int* __restrict__ cursor,
                                  float* __restrict__ rcnt) {
    __shared__ int sh[256];
    int t = threadIdx.x, i = blockIdx.x * 256 + t;
    int c0 = 0, c1 = 0, c2 = 0;
    if (i < NNODE) { c0 = cnt[3 * i]; c1 = cnt[3 * i + 1]; c2 = cnt[3 * i + 2]; }
    int v = c0 + c1 + c2;
    sh[t] = v; __syncthreads();
    for (int o = 1; o < 256; o <<= 1) {
        int x = (t >= o) ? sh[t - o] : 0; __syncthreads();
        sh[t] += x; __syncthreads();
    }
    int exc = sh[t] - v + partial_pre[blockIdx.x];
    if (i < NNODE) {
        offs[i] = exc; cursor[i] = exc;
        float4 rc = make_float4(1.f / fmaxf((float)c0, 1.f), 1.f / fmaxf((float)c1, 1.f),
                                1.f / fmaxf((float)c2, 1.f), 1.f);
        *(float4*)&rcnt[i * 4] = rc;
    }
}

// ---------------- fill: dst-sorted edge list, src|rel packed ----------------
__global__ void fill_kernel(const int* __restrict__ ei, const int* __restrict__ et,
                            int* __restrict__ cursor, int* __restrict__ sorted) {
    int e = blockIdx.x * blockDim.x + threadIdx.x;
    if (e >= NEDGE) return;
    int s = ei[e], d = ei[NEDGE + e], r = et[e];
    int p = atomicAdd(&cursor[d], 1);
    sorted[p] = s | (r << 16);   // NNODE < 65536, r < 4
}

// ---------------- layer-1 histogram: wave-per-node, lane-owned bins ----------------
__global__ __launch_bounds__(256) void hist1_kernel(const int* __restrict__ offs,
                                                    const int* __restrict__ sorted,
                                                    const int2* __restrict__ nf,
                                                    float* __restrict__ A1) {
    int lane = threadIdx.x & 63;
    int d = (blockIdx.x << 2) + (threadIdx.x >> 6);
    if (d >= NNODE) return;
    int beg = offs[d], end = offs[d + 1];
    // slot0 = lane (0..63), slot1 = lane+64 (64..127, valid < 99)
    int r0 = lane / 33, b0 = lane - r0 * 33;
    int s1 = lane + 64;
    int r1 = s1 / 33, b1 = s1 - r1 * 33;
    float acc0 = 0.f, acc1 = 0.f;
    for (int i = beg; i < end; ++i) {
        int w = sorted[i];
        int s = w & 0xFFFF, r = (w >> 16) & 3;
        int2 f = nf[s];
        int shape = f.x & 0xFF, color = f.x >> 8;
        float pv = __int_as_float(f.y);
        float c0 = (b0 < 16) ? ((b0 == shape) ? 1.f : 0.f)
                 : (b0 < 32) ? ((b0 - 16 == color) ? 1.f : 0.f) : pv;
        acc0 += (r == r0) ? c0 : 0.f;
        float c1 = (b1 < 16) ? ((b1 == shape) ? 1.f : 0.f)
                 : (b1 < 32) ? ((b1 - 16 == color) ? 1.f : 0.f) : pv;
        acc1 += (r == r1) ? c1 : 0.f;
    }
    float* row = &A1[(size_t)d * K1];
    row[lane] = acc0;
    if (lane < 48) row[64 + lane] = (lane < 35) ? acc1 : 0.f;
}

// ---------------- layer-2 aggregation: wave-per-node bf16 gather ----------------
__global__ __launch_bounds__(256) void aggregate_kernel(const int* __restrict__ offs,
                                                        const int* __restrict__ sorted,
                                                        const float* __restrict__ rcnt,
                                                        const unsigned short* __restrict__ x1b,
                                                        float* __restrict__ A2) {
    int lane = threadIdx.x & 63;
    int d = (blockIdx.x << 2) + (threadIdx.x >> 6);
    if (d >= NNODE) return;
    int beg = offs[d], end = offs[d + 1];
    float a00 = 0.f, a01 = 0.f, a10 = 0.f, a11 = 0.f, a20 = 0.f, a21 = 0.f;
    for (int i = beg; i < end; ++i) {
        int w = sorted[i];
        int s = w & 0xFFFF, r = (w >> 16) & 3;
        unsigned x = *(const unsigned*)(x1b + ((size_t)s << 7) + (lane << 1));
        float x0 = __uint_as_float(x << 16);
        float x1v = __uint_as_float(x & 0xFFFF0000u);
        if (r == 0)      { a00 += x0; a01 += x1v; }
        else if (r == 1) { a10 += x0; a11 += x1v; }
        else             { a20 += x0; a21 += x1v; }
    }
    float rc0 = rcnt[d * 4 + 0], rc1 = rcnt[d * 4 + 1], rc2 = rcnt[d * 4 + 2];
    float* o = &A2[(size_t)d * 512 + (lane << 1)];
    *(float2*)(o)       = make_float2(a00 * rc0, a01 * rc0);
    *(float2*)(o + 128) = make_float2(a10 * rc1, a11 * rc1);
    *(float2*)(o + 256) = make_float2(a20 * rc2, a21 * rc2);
}

// ---------------- layer-1 fused GEMM (fp32, 64x128 tile, 4x8 microtile) ----------------
__global__ __launch_bounds__(256) void gemm1_kernel(
    const float* __restrict__ A, const float* __restrict__ B,
    const float* __restrict__ rcnt,
    const int* __restrict__ shape_id, const int* __restrict__ color_id,
    const float* __restrict__ pos, const float* __restrict__ rootTab,
    const float* __restrict__ bias,
    float* __restrict__ Cout, unsigned short* __restrict__ x1b) {
    constexpr int K = K1, BM = 64, BK = 16;
    __shared__ float As[BK][BM + 4];
    __shared__ float Bs[BK][HIDD];
    const int t  = threadIdx.x;
    const int m0 = blockIdx.x * BM;
    const int tx = t & 15, ty = t >> 4;
    const int arow = t >> 2, ac4 = (t & 3) * 4;
    const int brow = t >> 4, bc = (t & 15) * 8;
    float acc[4][8] = {};
    for (int kt = 0; kt < K; kt += BK) {
        {
            int gr = m0 + arow;
            float4 v = make_float4(0.f, 0.f, 0.f, 0.f);
            if (gr < NNODE) {
                v = *(const float4*)&A[(size_t)gr * K + kt + ac4];
                float* vp = &v.x;
#pragma unroll
                for (int i = 0; i < 4; ++i) {
                    int kk = kt + ac4 + i;
                    int r = min(kk / 33, 3);
                    vp[i] *= rcnt[gr * 4 + r];
                }
            }
            As[ac4 + 0][arow] = v.x;
            As[ac4 + 1][arow] = v.y;
            As[ac4 + 2][arow] = v.z;
            As[ac4 + 3][arow] = v.w;
        }
        {
            const float4* src = (const float4*)&B[(size_t)(kt + brow) * HIDD + bc];
            *(float4*)&Bs[brow][bc]     = src[0];
            *(float4*)&Bs[brow][bc + 4] = src[1];
        }
        __syncthreads();
#pragma unroll
        for (int k = 0; k < BK; ++k) {
            float a[4], b[8];
            *(float4*)a      = *(const float4*)&As[k][ty * 4];
            *(float4*)&b[0]  = *(const float4*)&Bs[k][tx * 8];
            *(float4*)&b[4]  = *(const float4*)&Bs[k][tx * 8 + 4];
#pragma unroll
            for (int i = 0; i < 4; ++i)
#pragma unroll
                for (int j = 0; j < 8; ++j)
                    acc[i][j] = fmaf(a[i], b[j], acc[i][j]);
        }
        __syncthreads();
    }
#pragma unroll
    for (int i = 0; i < 4; ++i) {
        int gr = m0 + ty * 4 + i;
        if (gr >= NNODE) continue;
        int sid = shape_id[gr], cid = color_id[gr];
        float p = pos[gr];
        vshort8 p8;
#pragma unroll
        for (int j = 0; j < 8; ++j) {
            int h = tx * 8 + j;
            float v = acc[i][j] + rootTab[sid * 128 + h] + rootTab[(16 + cid) * 128 + h]
                    + p * rootTab[32 * 128 + h] + bias[h];
            float rv = fmaxf(v, 0.f);
            Cout[(size_t)gr * 512 + 384 + h] = rv;
            p8[j] = bf16_rne(rv);
        }
        *(vshort8*)&x1b[(size_t)gr * 128 + tx * 8] = p8;
    }
}

// ---------------- layer-2 GEMM: MFMA bf16x3 split (fp32-accurate) ----------------
__global__ __launch_bounds__(256) void gemm2_mfma_kernel(
    const float* __restrict__ A,
    const short* __restrict__ Bt_hi, const short* __restrict__ Bt_lo,
    const float* __restrict__ bias,
    float* __restrict__ x2) {
    __shared__ short Ah[4][128][8];
    __shared__ short Al[4][128][8];
    __shared__ short Bh[4][128][8];
    __shared__ short Bl[4][128][8];
    const int t    = threadIdx.x;
    const int lane = t & 63;
    const int w    = t >> 6;
    const int wm   = w >> 1, wn = w & 1;
    const int bm0  = blockIdx.x * 128;
    const int lr   = lane & 15, lk = lane >> 4;
    f32x4 acc[4][4] = {};
    for (int kt = 0; kt < K2; kt += 32) {
        __syncthreads();
#pragma unroll
        for (int p = 0; p < 4; ++p) {
            int idx = p * 256 + t;
            int row = idx >> 3;
            int kq  = (idx & 7) * 4;
            int gr  = bm0 + row;
            float4 v = make_float4(0.f, 0.f, 0.f, 0.f);
            if (gr < NNODE) v = *(const float4*)&A[(size_t)gr * K2 + kt + kq];
            vshort4 h4, l4;
            float* vp = &v.x;
#pragma unroll
            for (int i = 0; i < 4; ++i) { short hh, ll; split_bf16(vp[i], hh, ll); h4[i] = hh; l4[i] = ll; }
            int kb = kq >> 3, j0 = kq & 7;
            *(vshort4*)&Ah[kb][row][j0] = h4;
            *(vshort4*)&Al[kb][row][j0] = l4;
        }
#pragma unroll
        for (int p = 0; p < 2; ++p) {
            int idx = p * 256 + t;
            int n = idx >> 2, kb = idx & 3;
            *(vshort8*)&Bh[kb][n][0] = *(const vshort8*)&Bt_hi[(size_t)n * K2 + kt + kb * 8];
            *(vshort8*)&Bl[kb][n][0] = *(const vshort8*)&Bt_lo[(size_t)n * K2 + kt + kb * 8];
        }
        __syncthreads();
        vshort8 af_h[4], af_l[4], bf_h[4], bf_l[4];
#pragma unroll
        for (int f = 0; f < 4; ++f) {
            af_h[f] = *(const vshort8*)&Ah[lk][wm * 64 + f * 16 + lr][0];
            af_l[f] = *(const vshort8*)&Al[lk][wm * 64 + f * 16 + lr][0];
            bf_h[f] = *(const vshort8*)&Bh[lk][wn * 64 + f * 16 + lr][0];
            bf_l[f] = *(const vshort8*)&Bl[lk][wn * 64 + f * 16 + lr][0];
        }
#pragma unroll
        for (int mf = 0; mf < 4; ++mf)
#pragma unroll
            for (int nf = 0; nf < 4; ++nf) {
                acc[mf][nf] = __builtin_amdgcn_mfma_f32_16x16x32_bf16(af_h[mf], bf_h[nf], acc[mf][nf], 0, 0, 0);
                acc[mf][nf] = __builtin_amdgcn_mfma_f32_16x16x32_bf16(af_l[mf], bf_h[nf], acc[mf][nf], 0, 0, 0);
                acc[mf][nf] = __builtin_amdgcn_mfma_f32_16x16x32_bf16(af_h[mf], bf_l[nf], acc[mf][nf], 0, 0, 0);
            }
    }
#pragma unroll
    for (int mf = 0; mf < 4; ++mf) {
        int mb = bm0 + wm * 64 + mf * 16 + (lane >> 4) * 4;
#pragma unroll
        for (int nf = 0; nf < 4; ++nf) {
            int n = wn * 64 + nf * 16 + lr;
            float bn = bias[n];
#pragma unroll
            for (int r = 0; r < 4; ++r) {
                int gm = mb + r;
                if (gm < NNODE)
                    x2[(size_t)gm * HIDD + n] = fmaxf(acc[mf][nf][r] + bn, 0.f);
            }
        }
    }
}

// ---------------- pooling (batch sorted -> run-length reduce), 64 nodes/block ----------------
__global__ void pool_kernel(const float* __restrict__ x2, const int* __restrict__ batch,
                            float* __restrict__ pooled, float* __restrict__ cntg) {
    const int CH = 64;
    int h  = threadIdx.x; // 128
    int n0 = blockIdx.x * CH;
    if (n0 >= NNODE) return;
    int n1 = min(n0 + CH, NNODE);
    int cur = batch[n0];
    float acc = 0.f;
    int run = 0;
    for (int n = n0; n < n1; ++n) {
        int g = batch[n];
        if (g != cur) {
            atomicAdd(&pooled[cur * 128 + h], acc);
            if (h == 0) atomicAdd(&cntg[cur], (float)run);
            acc = 0.f; run = 0; cur = g;
        }
        acc += x2[(size_t)n * 128 + h];
        ++run;
    }
    atomicAdd(&pooled[cur * 128 + h], acc);
    if (h == 0) atomicAdd(&cntg[cur], (float)run);
}

__global__ void final_kernel(const float* __restrict__ pooled, const float* __restrict__ cntg,
                             const float* __restrict__ lin_w, const float* __restrict__ lin_b,
                             float* __restrict__ out) {
    int idx = blockIdx.x * blockDim.x + threadIdx.x;
    if (idx >= GNUM * 4) return;
    int g = idx >> 2, c = idx & 3;
    float dot = 0.f;
    for (int k = 0; k < 128; ++k) dot += pooled[g * 128 + k] * lin_w[k * 4 + c];
    out[idx] = dot / fmaxf(cntg[g], 1.f) + lin_b[c];
}

// ---------------- launch ----------------
extern "C" void kernel_launch(void* const* d_in, const int* in_sizes, int n_in,
                              void* d_out, int out_size, void* d_ws, size_t ws_size,
                              hipStream_t stream) {
    const float* pos      = (const float*)d_in[0];
    const int*   shape_id = (const int*)d_in[1];
    const int*   color_id = (const int*)d_in[2];
    const int*   ei       = (const int*)d_in[3];
    const int*   et       = (const int*)d_in[4];
    const int*   batch    = (const int*)d_in[5];
    const float* shape_w  = (const float*)d_in[6];
    const float* color_w  = (const float*)d_in[7];
    const float* W1       = (const float*)d_in[8];
    const float* root1    = (const float*)d_in[9];
    const float* b1       = (const float*)d_in[10];
    const float* W2       = (const float*)d_in[11];
    const float* root2    = (const float*)d_in[12];
    const float* b2       = (const float*)d_in[13];
    const float* lin_w    = (const float*)d_in[14];
    const float* lin_b    = (const float*)d_in[15];
    float* out = (float*)d_out;

    char* p = (char*)d_ws;
    auto alloc = [&](size_t bytes) { char* r = p; p += (bytes + 255) & ~(size_t)255; return r; };
    int*   cnt     = (int*)alloc((size_t)NNODE * 3 * 4);
    float* A1      = (float*)alloc((size_t)NNODE * K1 * 4);
    float* rcntBuf = (float*)alloc((size_t)NNODE * 4 * 4);
    float* A2      = (float*)alloc((size_t)NNODE * 512 * 4);
    float* x2      = (float*)alloc((size_t)NNODE * 128 * 4);
    unsigned short* x1b = (unsigned short*)alloc((size_t)NNODE * 128 * 2);
    float* B1eff   = (float*)alloc((size_t)K1 * 128 * 4);
    float* rootTab = (float*)alloc((size_t)33 * 128 * 4);
    short* Bt_hi   = (short*)alloc((size_t)128 * K2 * 2);
    short* Bt_lo   = (short*)alloc((size_t)128 * K2 * 2);
    float* pooled  = (float*)alloc((size_t)GNUM * 128 * 4);
    float* cntg    = (float*)alloc((size_t)GNUM * 4);
    int2*  nfTab   = (int2*)alloc((size_t)NNODE * 8);
    // CSR temporaries alias into x2 (all consumed before gemm2 writes x2)
    char* xb = (char*)x2;
    int* sorted     = (int*)(xb);                       // E ints = 2.56 MB
    int* offs       = (int*)(xb + 2600960);             // NNODE+1 ints
    int* cursor     = (int*)(xb + 2900992);             // NNODE ints
    int* partial    = (int*)(xb + 3200000);             // NB ints
    int* partialPre = (int*)(xb + 3210240);             // NB ints

    hipMemsetAsync(cnt,    0, (size_t)NNODE * 3 * 4, stream);
    hipMemsetAsync(B1eff,  0, (size_t)K1 * 128 * 4, stream);
    hipMemsetAsync(pooled, 0, (size_t)GNUM * 128 * 4, stream);
    hipMemsetAsync(cntg,   0, (size_t)GNUM * 4, stream);

    build_tabs_kernel<<<(4 * 33 * 128 + 255) / 256, 256, 0, stream>>>(
        shape_w, color_w, W1, root1, B1eff, rootTab);
    build_B2t_kernel<<<(K2 * 128 + 255) / 256, 256, 0, stream>>>(W2, root2, Bt_hi, Bt_lo);

    count_nf_kernel<<<(NEDGE + 255) / 256, 256, 0, stream>>>(
        ei, et, shape_id, color_id, pos, cnt, nfTab);
    scan_partial_kernel<<<NB, 256, 0, stream>>>(cnt, partial);
    scan_mid_kernel<<<1, 256, 0, stream>>>(partial, partialPre, offs);
    scan_final_kernel<<<NB, 256, 0, stream>>>(cnt, partialPre, offs, cursor, rcntBuf);
    fill_kernel<<<(NEDGE + 255) / 256, 256, 0, stream>>>(ei, et, cursor, sorted);

    hist1_kernel<<<(NNODE + 3) / 4, 256, 0, stream>>>(offs, sorted, nfTab, A1);

    gemm1_kernel<<<(NNODE + 63) / 64, 256, 0, stream>>>(
        A1, B1eff, rcntBuf, shape_id, color_id, pos, rootTab, b1, A2, x1b);

    aggregate_kernel<<<(NNODE + 3) / 4, 256, 0, stream>>>(offs, sorted, rcntBuf, x1b, A2);

    gemm2_mfma_kernel<<<(NNODE + 127) / 128, 256, 0, stream>>>(
        A2, Bt_hi, Bt_lo, b2, x2);

    pool_kernel<<<(NNODE + 63) / 64, 128, 0, stream>>>(x2, batch, pooled, cntg);

    final_kernel<<<(GNUM * 4 + 255) / 256, 256, 0, stream>>>(
        pooled, cntg, lin_w, lin_b, out);
}